// Round 11
// baseline (140.301 us; speedup 1.0000x reference)
//
#include <hip/hip_runtime.h>
#include <hip/hip_bf16.h>
#include <stdint.h>

// Problem constants
#define S_LEN 2048
#define DM    1024
#define NH    16
#define DKH   64
#define BATCH 2
#define M_ROWS (BATCH * S_LEN)   // 4096
#define NQKV   (3 * DM)          // 3072

typedef short          bf16x8v __attribute__((ext_vector_type(8)));
typedef float          f32x4   __attribute__((ext_vector_type(4)));
typedef float          f32x16  __attribute__((ext_vector_type(16)));
typedef unsigned short u16x4   __attribute__((ext_vector_type(4)));
typedef unsigned short u16x8   __attribute__((ext_vector_type(8)));
typedef unsigned int   u32x2   __attribute__((ext_vector_type(2)));
typedef unsigned int   u32x4   __attribute__((ext_vector_type(4)));

typedef const void __attribute__((address_space(1))) gas_void;
typedef void       __attribute__((address_space(3))) las_void;

static __device__ __forceinline__ unsigned short f2bf(float f) {
    union { float f; uint32_t u; } v; v.f = f;
    uint32_t u = v.u;
    uint32_t r = (u + 0x7fffu + ((u >> 16) & 1u)) >> 16;  // RNE
    return (unsigned short)r;
}

// raw v_exp_f32: D = 2^S0
static __device__ __forceinline__ float exp2_hw(float x) {
    float r;
    asm("v_exp_f32 %0, %1" : "=v"(r) : "v"(x));
    return r;
}

// pack 2 f32 -> 2 bf16 in one u32 (lo = first arg)
static __device__ __forceinline__ uint32_t cvtpk_bf16(float lo, float hi) {
    uint32_t r;
    asm("v_cvt_pk_bf16_f32 %0, %1, %2" : "=v"(r) : "v"(lo), "v"(hi));
    return r;
}
// swap: new_a = {a[0:31], b[0:31]}, new_b = {a[32:63], b[32:63]}
static __device__ __forceinline__ u32x2 pl32swap(uint32_t a, uint32_t b) {
    return __builtin_amdgcn_permlane32_swap(a, b, false, false);
}
static __device__ __forceinline__ float    fbits(uint32_t u) { return __builtin_bit_cast(float, u); }
static __device__ __forceinline__ uint32_t ubits(float f)    { return __builtin_bit_cast(uint32_t, f); }

// ---------------- fp32 -> bf16 elementwise (x) ----------------
__global__ __launch_bounds__(256) void cvt_bf16_kernel(
    const float* __restrict__ in, unsigned short* __restrict__ out, int n8)
{
    const int i = blockIdx.x * 256 + threadIdx.x;
    if (i >= n8) return;
    f32x4 a = *(const f32x4*)(in + (size_t)i * 8);
    f32x4 b = *(const f32x4*)(in + (size_t)i * 8 + 4);
    u16x8 o;
    #pragma unroll
    for (int j = 0; j < 4; ++j) { o[j] = f2bf(a[j]); o[4 + j] = f2bf(b[j]); }
    *(u16x8*)(out + (size_t)i * 8) = o;
}

// ---------------- W [K][N] fp32 -> Wt [N][K] bf16 (tiled transpose) ----------------
__global__ __launch_bounds__(256) void transpose_w_kernel(
    const float* __restrict__ W, unsigned short* __restrict__ Wt, int K, int N)
{
    __shared__ float t[32][33];
    const int tx = threadIdx.x, ty = threadIdx.y;
    const int n0 = blockIdx.x * 32, k0 = blockIdx.y * 32;
    #pragma unroll
    for (int i = 0; i < 4; ++i)
        t[ty * 4 + i][tx] = W[(size_t)(k0 + ty * 4 + i) * N + n0 + tx];
    __syncthreads();
    #pragma unroll
    for (int i = 0; i < 4; ++i)
        Wt[(size_t)(n0 + ty * 4 + i) * K + k0 + tx] = f2bf(t[tx][ty * 4 + i]);
}

// ---------------- GEMM: C[M][N] = A[M][K] * Bt[N][K]^T + bias ----------------
template <int EPI>
__global__ __launch_bounds__(256) void gemm_bt_kernel(
    const unsigned short* __restrict__ A, const unsigned short* __restrict__ Bt,
    const float* __restrict__ bias, void* __restrict__ Cout,
    int M, int N, int K)
{
    __shared__ __attribute__((aligned(16))) unsigned short As[128 * 32];
    __shared__ __attribute__((aligned(16))) unsigned short Bs[128 * 32];

    const int tid  = threadIdx.x;
    const int lane = tid & 63;
    const int w    = tid >> 6;
    const int wr   = w >> 1, wc = w & 1;
    const int lr   = lane & 15, lg = lane >> 4;
    const int m0   = blockIdx.y * 128, n0 = blockIdx.x * 128;

    f32x4 acc[4][4];
    #pragma unroll
    for (int i = 0; i < 4; ++i)
        #pragma unroll
        for (int j = 0; j < 4; ++j) acc[i][j] = (f32x4){0.f, 0.f, 0.f, 0.f};

    for (int kt = 0; kt < K; kt += 32) {
        if (kt) __syncthreads();
        #pragma unroll
        for (int j = 0; j < 2; ++j) {
            const int c  = j * 256 + tid;
            const int r  = c >> 2;
            const int kc = (c & 3) * 8;
            const int cb = j * 256 + (tid & ~63);
            __builtin_amdgcn_global_load_lds(
                (gas_void*)(A + (size_t)(m0 + r) * K + kt + kc),
                (las_void*)((char*)As + (size_t)cb * 16), 16, 0, 0);
            __builtin_amdgcn_global_load_lds(
                (gas_void*)(Bt + (size_t)(n0 + r) * K + kt + kc),
                (las_void*)((char*)Bs + (size_t)cb * 16), 16, 0, 0);
        }
        __syncthreads();

        bf16x8v af[4], bfv[4];
        #pragma unroll
        for (int mi = 0; mi < 4; ++mi)
            af[mi] = *(const bf16x8v*)(&As[(wr * 64 + mi * 16 + lr) * 32 + lg * 8]);
        #pragma unroll
        for (int ni = 0; ni < 4; ++ni)
            bfv[ni] = *(const bf16x8v*)(&Bs[(wc * 64 + ni * 16 + lr) * 32 + lg * 8]);
        #pragma unroll
        for (int mi = 0; mi < 4; ++mi)
            #pragma unroll
            for (int ni = 0; ni < 4; ++ni)
                acc[mi][ni] = __builtin_amdgcn_mfma_f32_16x16x32_bf16(
                    af[mi], bfv[ni], acc[mi][ni], 0, 0, 0);
    }

    const int grow0 = m0 + wr * 64 + lg * 4;
    const int gcol0 = n0 + wc * 64 + lr;
    #pragma unroll
    for (int mi = 0; mi < 4; ++mi)
        #pragma unroll
        for (int ni = 0; ni < 4; ++ni) {
            const int gcol = gcol0 + ni * 16;
            const float bv = bias[gcol];
            #pragma unroll
            for (int r = 0; r < 4; ++r) {
                const size_t idx = (size_t)(grow0 + mi * 16 + r) * N + gcol;
                const float v = acc[mi][ni][r] + bv;
                if (EPI == 0) ((unsigned short*)Cout)[idx] = f2bf(v);
                else          ((float*)Cout)[idx] = v;
            }
        }
}

// ---------------- split V only: qkv V-block -> Vt [bh][64][s] ----------------
__global__ __launch_bounds__(256) void split_v_kernel(
    const unsigned short* __restrict__ qkv, unsigned short* __restrict__ vt)
{
    const int tid = threadIdx.x;
    const int bh  = blockIdx.y;
    const int h   = bh & 15;
    const int b   = bh >> 4;
    const int s0  = blockIdx.x * 64;
    __shared__ __attribute__((aligned(16))) unsigned short tile[64][68];

    #pragma unroll
    for (int j = 0; j < 4; ++j) {
        const int c  = tid + j * 256;      // 0..1023 (chunks of 4 ushorts)
        const int r  = c >> 4;             // s row 0..63
        const int c4 = (c & 15) * 4;       // dk col 0..60
        const size_t srow = ((size_t)b * S_LEN + s0 + r) * NQKV + 2 * DM + h * 64 + c4;
        *(u16x4*)&tile[r][c4] = *(const u16x4*)(qkv + srow);
    }
    __syncthreads();
    #pragma unroll
    for (int j = 0; j < 4; ++j) {
        const int c   = tid + j * 256;
        const int dkr = c >> 4;            // dk row of Vt
        const int s4  = (c & 15) * 4;      // s col
        u16x4 o;
        #pragma unroll
        for (int i = 0; i < 4; ++i) o[i] = tile[s4 + i][dkr];
        *(u16x4*)(vt + ((size_t)bh * DKH + dkr) * S_LEN + s0 + s4) = o;
    }
}

// ---------------- flash attention: 8-wave block, KV-split x2, static softmax ----
// Block = 512 threads = 8 waves = 4 q-tiles x 2 kv-halves. Wave w: q-tile w>>1
// (32 rows), kv-half w&1 (kv in [kh*1024, +1024), 16 tiles of 64). Grid = 512
// blocks = 2 blocks/CU -> 4096 waves = 4 waves/SIMD (2x R10's TLP).
// STATIC softmax max (=0): partial-KV merge is PLAIN SUMMATION of acc+lsum --
// no exp-weighted rescale needed. Merge via dead staging LDS at the end.
// Per tile-iter both halves' K/V staged (4 x 8KB, dbuf); every wave computes
// every iteration; per-wave barrier/exp chain HALVES (16 iters vs 32).
#define EXP_C1 0.18033688f   /* 0.125 * log2(e) : softmax temp in exp2 domain */
#define KVB 64

static __device__ __forceinline__ int swzkey(int r) { return (r ^ (r >> 3)) & 7; }

#define LDS_SUB_STEP(KsB, VsB, ks)                                                   \
do {                                                                                 \
    /* operand fragments from LDS (swizzled chunk addressing) */                     \
    bf16x8v kc_[4], vc_[4];                                                          \
    _Pragma("unroll")                                                                \
    for (int s_ = 0; s_ < 4; ++s_) {                                                 \
        const int r_ = (ks) + lo;                                                    \
        kc_[s_] = *(const bf16x8v*)((KsB) + r_ * 128 +                               \
                                    (((s_ * 2 + hi) ^ swzkey(r_)) << 4));            \
    }                                                                                \
    _Pragma("unroll")                                                                \
    for (int j_ = 0; j_ < 4; ++j_) {                                                 \
        const int r_ = (j_ >> 1) * 32 + lo;                                          \
        const int cc_ = ((ks) >> 3) + (j_ & 1) * 2 + hi;                             \
        vc_[j_] = *(const bf16x8v*)((VsB) + r_ * 128 +                               \
                                    ((cc_ ^ swzkey(r_)) << 4));                      \
    }                                                                                \
    f32x16 scA = {}, scB = {};                                                       \
    __builtin_amdgcn_s_setprio(1);                                                   \
    scA = __builtin_amdgcn_mfma_f32_32x32x16_bf16(kc_[0], qf[0], scA, 0, 0, 0);      \
    scB = __builtin_amdgcn_mfma_f32_32x32x16_bf16(kc_[1], qf[1], scB, 0, 0, 0);      \
    scA = __builtin_amdgcn_mfma_f32_32x32x16_bf16(kc_[2], qf[2], scA, 0, 0, 0);      \
    scB = __builtin_amdgcn_mfma_f32_32x32x16_bf16(kc_[3], qf[3], scB, 0, 0, 0);      \
    __builtin_amdgcn_s_setprio(0);                                                   \
    f32x16 sc = scA + scB;                                                           \
    /* static softmax: p = 2^(sc * c1), no running max */                            \
    float pe_[16];                                                                   \
    _Pragma("unroll")                                                                \
    for (int r_ = 0; r_ < 16; ++r_)                                                  \
        pe_[r_] = exp2_hw(sc[r_] * EXP_C1);                                          \
    float u0_ = (pe_[0] + pe_[1]) + (pe_[2] + pe_[3]);                               \
    float u1_ = (pe_[4] + pe_[5]) + (pe_[6] + pe_[7]);                               \
    float u2_ = (pe_[8] + pe_[9]) + (pe_[10] + pe_[11]);                             \
    float u3_ = (pe_[12] + pe_[13]) + (pe_[14] + pe_[15]);                           \
    float ss_ = (u0_ + u1_) + (u2_ + u3_);                                           \
    { u32x2 sw_ = pl32swap(ubits(ss_), ubits(ss_));                                  \
      ss_ = fbits(sw_[0]) + fbits(sw_[1]); }                                         \
    lsum += ss_;                                                                     \
    /* P -> bf16 B-fragments: cvt_pk pairs + permlane32_swap (T12 recipe) */         \
    uint32_t a01_ = cvtpk_bf16(pe_[0],  pe_[1]),  a23_ = cvtpk_bf16(pe_[2],  pe_[3]);  \
    uint32_t a45_ = cvtpk_bf16(pe_[4],  pe_[5]),  a67_ = cvtpk_bf16(pe_[6],  pe_[7]);  \
    uint32_t b01_ = cvtpk_bf16(pe_[8],  pe_[9]),  b23_ = cvtpk_bf16(pe_[10], pe_[11]); \
    uint32_t b45_ = cvtpk_bf16(pe_[12], pe_[13]), b67_ = cvtpk_bf16(pe_[14], pe_[15]); \
    u32x2 s0_ = pl32swap(a01_, a45_);                                                \
    u32x2 s1_ = pl32swap(a23_, a67_);                                                \
    u32x2 s2_ = pl32swap(b01_, b45_);                                                \
    u32x2 s3_ = pl32swap(b23_, b67_);                                                \
    u32x4 w0_ = { s0_[0], s1_[0], s0_[1], s1_[1] };                                  \
    u32x4 w1_ = { s2_[0], s3_[0], s2_[1], s3_[1] };                                  \
    bf16x8v pa0_ = __builtin_bit_cast(bf16x8v, w0_);                                 \
    bf16x8v pa1_ = __builtin_bit_cast(bf16x8v, w1_);                                 \
    __builtin_amdgcn_s_setprio(1);                                                   \
    acc0 = __builtin_amdgcn_mfma_f32_32x32x16_bf16(vc_[0], pa0_, acc0, 0, 0, 0);     \
    acc0 = __builtin_amdgcn_mfma_f32_32x32x16_bf16(vc_[1], pa1_, acc0, 0, 0, 0);     \
    acc1 = __builtin_amdgcn_mfma_f32_32x32x16_bf16(vc_[2], pa0_, acc1, 0, 0, 0);     \
    acc1 = __builtin_amdgcn_mfma_f32_32x32x16_bf16(vc_[3], pa1_, acc1, 0, 0, 0);     \
    __builtin_amdgcn_s_setprio(0);                                                   \
} while (0)

__global__ __launch_bounds__(512, 2) void attn_kernel(
    const unsigned short* __restrict__ QKV, const unsigned short* __restrict__ Vt,
    unsigned short* __restrict__ O)
{
    const int tid  = threadIdx.x;
    const int w    = tid >> 6;         // wave 0..7
    const int qt   = w >> 1;           // q-tile within block (0..3)
    const int kh   = w & 1;            // kv half (0/1)
    const int lane = tid & 63;
    const int lo = lane & 31;
    const int hi = lane >> 5;

    // T1: XCD-chunked bijective swizzle; 512 blocks = 8 XCDs x 64.
    const int flat = blockIdx.x;
    const int virt = (flat & 7) * 64 + (flat >> 3);
    const int bh = virt >> 4;          // 0..31
    const int qb = virt & 15;          // 0..15
    const int b = bh >> 4, h = bh & 15;
    const int q0 = qb * 128 + qt * 32;

    // Staged K/V tiles: [buf][half][64*64] bf16 = 8 KB each -> 64 KB total.
    __shared__ __attribute__((aligned(16))) unsigned short Ks[2][2][KVB * 64];
    __shared__ __attribute__((aligned(16))) unsigned short Vs[2][2][KVB * 64];

    // K rows live in qkv: row (b*S + kv), cols [DM + h*64, +64)
    const unsigned short* Kq  = QKV + (size_t)b * S_LEN * NQKV + DM + h * 64;
    const unsigned short* Vtb = Vt + (size_t)bh * DKH * S_LEN;   // [64][2048]

    // staging map: one 8 KB tile = 512 chunks (16B); 512 threads -> 1 chunk each.
    // thread t: row sr = t>>3, slot scn = t&7; slot holds global chunk scn^key(sr).
    // Dest linear: wave-uniform base + lane*16.
    const int sr  = tid >> 3, scn = tid & 7;
    const size_t kSrc = (size_t)sr * NQKV  + ((scn ^ swzkey(sr)) * 8);
    const size_t vSrc = (size_t)sr * S_LEN + ((scn ^ swzkey(sr)) * 8);
    const int dstOff = (tid & ~63) * 16;   // bytes 0..8191

#define STAGE_TILE(buf, t)                                                            \
    do {                                                                              \
        const size_t kv0_ = (size_t)(t) * KVB;                                        \
        __builtin_amdgcn_global_load_lds((gas_void*)(Kq + kv0_ * NQKV + kSrc),        \
            (las_void*)((char*)&Ks[buf][0][0] + dstOff), 16, 0, 0);                   \
        __builtin_amdgcn_global_load_lds((gas_void*)(Kq + (kv0_ + 1024) * NQKV + kSrc),\
            (las_void*)((char*)&Ks[buf][1][0] + dstOff), 16, 0, 0);                   \
        __builtin_amdgcn_global_load_lds((gas_void*)(Vtb + kv0_ + vSrc),              \
            (las_void*)((char*)&Vs[buf][0][0] + dstOff), 16, 0, 0);                   \
        __builtin_amdgcn_global_load_lds((gas_void*)(Vtb + kv0_ + 1024 + vSrc),       \
            (las_void*)((char*)&Vs[buf][1][0] + dstOff), 16, 0, 0);                   \
    } while (0)

    // Q fragments (B-operand) straight from qkv: row (b*S + q0+lo), cols h*64 + ...
    const unsigned short* Qp =
        QKV + ((size_t)b * S_LEN + q0 + lo) * NQKV + h * 64 + hi * 8;
    bf16x8v qf[4];
    #pragma unroll
    for (int s = 0; s < 4; ++s) qf[s] = *(const bf16x8v*)(Qp + s * 16);

    f32x16 acc0 = {}, acc1 = {};       // out^T: rows d = n*32 + crow(r,hi), col q = lo
    float lsum = 0.f;

    // prologue: stage tile-pair 0 into buffer 0
    STAGE_TILE(0, 0);
    __syncthreads();   // drains vmcnt before barrier

    int cur = 0;
    for (int t = 0; t < S_LEN / (2 * KVB); ++t) {   // 16 iterations
        const int nxt = cur ^ 1;
        if (t + 1 < S_LEN / (2 * KVB)) STAGE_TILE(nxt, t + 1);
        const char* KsB = (const char*)&Ks[cur][kh][0];
        const char* VsB = (const char*)&Vs[cur][kh][0];
        LDS_SUB_STEP(KsB, VsB, 0);
        LDS_SUB_STEP(KsB, VsB, 32);
        __syncthreads();   // stage landed + all waves done reading buf[cur]
        cur = nxt;
    }
#undef STAGE_TILE

    // ---- merge kv-halves: PLAIN SUM (static max) via dead staging LDS ----
    // pair p = qt; partials region: Ks (32 KB) = 4 pairs x 32x64 f32; lsum in Vs.
    float* accbuf = (float*)&Ks[0][0][0] + qt * 2048;   // [i][lane] = [i*64+lane]
    float* lsbuf  = (float*)&Vs[0][0][0] + qt * 64;
    if (kh == 1) {
        #pragma unroll
        for (int i = 0; i < 16; ++i) {
            accbuf[i * 64 + lane]        = acc0[i];
            accbuf[(16 + i) * 64 + lane] = acc1[i];
        }
        lsbuf[lane & 63] = lsum;   // note: only lanes' own slot
    }
    __syncthreads();
    if (kh == 0) {
        #pragma unroll
        for (int i = 0; i < 16; ++i) {
            acc0[i] += accbuf[i * 64 + lane];
            acc1[i] += accbuf[(16 + i) * 64 + lane];
        }
        lsum += lsbuf[lane];

        const float linv = 1.f / lsum;
        // lane writes row q = q0+lo, cols h*64 + {n*32 + 8g + 4hi + 0..3}
        unsigned short* Orow = O + ((size_t)b * S_LEN + q0 + lo) * DM + h * 64 + hi * 4;
        #pragma unroll
        for (int g = 0; g < 4; ++g) {
            u16x4 st0, st1;
            #pragma unroll
            for (int k2 = 0; k2 < 4; ++k2) {
                st0[k2] = f2bf(acc0[g * 4 + k2] * linv);
                st1[k2] = f2bf(acc1[g * 4 + k2] * linv);
            }
            *(u16x4*)(Orow + g * 8)      = st0;
            *(u16x4*)(Orow + 32 + g * 8) = st1;
        }
    }
}

// ---------------- host launcher ----------------
extern "C" void kernel_launch(void* const* d_in, const int* in_sizes, int n_in,
                              void* d_out, int out_size, void* d_ws, size_t ws_size,
                              hipStream_t stream)
{
    const float* x    = (const float*)d_in[0];
    const float* Wqkv = (const float*)d_in[1];
    const float* bqkv = (const float*)d_in[2];
    const float* Wout = (const float*)d_in[3];
    const float* bout = (const float*)d_in[4];
    float* out = (float*)d_out;

    char* ws = (char*)d_ws;
    // layout (bytes):
    //  [0,         8388608)  xb (x bf16; dead after QKV GEMM)
    //  [8388608,  14680064)  wqkv_t bf16 [3072][1024]
    //  [14680064, 16777216)  wout_t bf16 [1024][1024]
    //  [16777216, 41943040)  qkvb bf16 [4096][3072]  (LIVE through attn: Q,K read from it)
    //  [41943040, 50331648)  attn_o bf16 [4096][1024]
    //  [50331648, 58720256)  vtb bf16 [32][64][2048]
    unsigned short* xb     = (unsigned short*)(ws);
    unsigned short* wqkv_t = (unsigned short*)(ws + 8388608);
    unsigned short* wout_t = (unsigned short*)(ws + 14680064);
    unsigned short* qkvb   = (unsigned short*)(ws + 16777216);
    unsigned short* attn_o = (unsigned short*)(ws + 41943040);
    unsigned short* vtb    = (unsigned short*)(ws + 50331648);

    cvt_bf16_kernel<<<2048, 256, 0, stream>>>(x, xb, (M_ROWS * DM) / 8);
    transpose_w_kernel<<<dim3(NQKV / 32, DM / 32), dim3(32, 8), 0, stream>>>(Wqkv, wqkv_t, DM, NQKV);
    transpose_w_kernel<<<dim3(DM / 32, DM / 32), dim3(32, 8), 0, stream>>>(Wout, wout_t, DM, DM);
    gemm_bt_kernel<0><<<dim3(NQKV / 128, M_ROWS / 128), 256, 0, stream>>>(
        xb, wqkv_t, bqkv, (void*)qkvb, M_ROWS, NQKV, DM);
    split_v_kernel<<<dim3(S_LEN / 64, BATCH * NH), 256, 0, stream>>>(qkvb, vtb);
    attn_kernel<<<512, 512, 0, stream>>>(qkvb, vtb, attn_o);
    gemm_bt_kernel<1><<<dim3(DM / 128, M_ROWS / 128), 256, 0, stream>>>(
        attn_o, wout_t, bout, (void*)out, M_ROWS, DM, DM);
}

// Round 12
// 135.397 us; speedup vs baseline: 1.0362x; 1.0362x over previous
//
#include <hip/hip_runtime.h>
#include <hip/hip_bf16.h>
#include <stdint.h>

// Problem constants
#define S_LEN 2048
#define DM    1024
#define NH    16
#define DKH   64
#define BATCH 2
#define M_ROWS (BATCH * S_LEN)   // 4096
#define NQKV   (3 * DM)          // 3072

typedef short          bf16x8v __attribute__((ext_vector_type(8)));
typedef float          f32x4   __attribute__((ext_vector_type(4)));
typedef float          f32x16  __attribute__((ext_vector_type(16)));
typedef unsigned short u16x4   __attribute__((ext_vector_type(4)));
typedef unsigned short u16x8   __attribute__((ext_vector_type(8)));
typedef unsigned int   u32x2   __attribute__((ext_vector_type(2)));
typedef unsigned int   u32x4   __attribute__((ext_vector_type(4)));

typedef const void __attribute__((address_space(1))) gas_void;
typedef void       __attribute__((address_space(3))) las_void;

static __device__ __forceinline__ unsigned short f2bf(float f) {
    union { float f; uint32_t u; } v; v.f = f;
    uint32_t u = v.u;
    uint32_t r = (u + 0x7fffu + ((u >> 16) & 1u)) >> 16;  // RNE
    return (unsigned short)r;
}

// raw v_exp_f32: D = 2^S0
static __device__ __forceinline__ float exp2_hw(float x) {
    float r;
    asm("v_exp_f32 %0, %1" : "=v"(r) : "v"(x));
    return r;
}

// pack 2 f32 -> 2 bf16 in one u32 (lo = first arg)
static __device__ __forceinline__ uint32_t cvtpk_bf16(float lo, float hi) {
    uint32_t r;
    asm("v_cvt_pk_bf16_f32 %0, %1, %2" : "=v"(r) : "v"(lo), "v"(hi));
    return r;
}
// swap: new_a = {a[0:31], b[0:31]}, new_b = {a[32:63], b[32:63]}
static __device__ __forceinline__ u32x2 pl32swap(uint32_t a, uint32_t b) {
    return __builtin_amdgcn_permlane32_swap(a, b, false, false);
}
static __device__ __forceinline__ float    fbits(uint32_t u) { return __builtin_bit_cast(float, u); }
static __device__ __forceinline__ uint32_t ubits(float f)    { return __builtin_bit_cast(uint32_t, f); }

// ---------------- fused prep: x->bf16 + W transposes (3 kernels in 1) ----------
// blocks [0,2048): cvt x; [2048,5120): transpose Wqkv; [5120,6144): transpose Wout.
__global__ __launch_bounds__(256) void prep_kernel(
    const float* __restrict__ x, unsigned short* __restrict__ xb,
    const float* __restrict__ Wqkv, unsigned short* __restrict__ wqkv_t,
    const float* __restrict__ Wout, unsigned short* __restrict__ wout_t)
{
    const int bid = blockIdx.x;
    const int tid = threadIdx.x;
    __shared__ float t[32][33];

    if (bid < 2048) {
        const int i = bid * 256 + tid;
        f32x4 a = *(const f32x4*)(x + (size_t)i * 8);
        f32x4 b = *(const f32x4*)(x + (size_t)i * 8 + 4);
        u16x8 o;
        #pragma unroll
        for (int j = 0; j < 4; ++j) { o[j] = f2bf(a[j]); o[4 + j] = f2bf(b[j]); }
        *(u16x8*)(xb + (size_t)i * 8) = o;
        return;
    }
    const float* W; unsigned short* Wt; int N, tb;
    if (bid < 2048 + 3072) { W = Wqkv; Wt = wqkv_t; N = NQKV; tb = bid - 2048; }
    else                   { W = Wout; Wt = wout_t; N = DM;   tb = bid - 5120; }
    const int K  = DM;
    const int nb = N / 32;
    const int n0 = (tb % nb) * 32, k0 = (tb / nb) * 32;
    const int tx = tid & 31, ty = tid >> 5;
    #pragma unroll
    for (int i = 0; i < 4; ++i)
        t[ty * 4 + i][tx] = W[(size_t)(k0 + ty * 4 + i) * N + n0 + tx];
    __syncthreads();
    #pragma unroll
    for (int i = 0; i < 4; ++i)
        Wt[(size_t)(n0 + ty * 4 + i) * K + k0 + tx] = f2bf(t[tx][ty * 4 + i]);
}

// ---------------- GEMM: C[M][N] = A[M][K] * Bt[N][K]^T + bias ----------------
// EPI==0: bf16 output; V-region blocks (n0 >= 2*DM, qkv only) write TRANSPOSED
// into vt[bh][dk][s] instead of C (fused split_v; qkv V-region is never read).
// EPI==1: fp32 output.
template <int EPI>
__global__ __launch_bounds__(256) void gemm_bt_kernel(
    const unsigned short* __restrict__ A, const unsigned short* __restrict__ Bt,
    const float* __restrict__ bias, void* __restrict__ Cout,
    unsigned short* __restrict__ vt,
    int M, int N, int K)
{
    __shared__ __attribute__((aligned(16))) unsigned short As[128 * 32];
    __shared__ __attribute__((aligned(16))) unsigned short Bs[128 * 32];

    const int tid  = threadIdx.x;
    const int lane = tid & 63;
    const int w    = tid >> 6;
    const int wr   = w >> 1, wc = w & 1;
    const int lr   = lane & 15, lg = lane >> 4;
    const int m0   = blockIdx.y * 128, n0 = blockIdx.x * 128;

    f32x4 acc[4][4];
    #pragma unroll
    for (int i = 0; i < 4; ++i)
        #pragma unroll
        for (int j = 0; j < 4; ++j) acc[i][j] = (f32x4){0.f, 0.f, 0.f, 0.f};

    for (int kt = 0; kt < K; kt += 32) {
        if (kt) __syncthreads();
        #pragma unroll
        for (int j = 0; j < 2; ++j) {
            const int c  = j * 256 + tid;
            const int r  = c >> 2;
            const int kc = (c & 3) * 8;
            const int cb = j * 256 + (tid & ~63);
            __builtin_amdgcn_global_load_lds(
                (gas_void*)(A + (size_t)(m0 + r) * K + kt + kc),
                (las_void*)((char*)As + (size_t)cb * 16), 16, 0, 0);
            __builtin_amdgcn_global_load_lds(
                (gas_void*)(Bt + (size_t)(n0 + r) * K + kt + kc),
                (las_void*)((char*)Bs + (size_t)cb * 16), 16, 0, 0);
        }
        __syncthreads();

        bf16x8v af[4], bfv[4];
        #pragma unroll
        for (int mi = 0; mi < 4; ++mi)
            af[mi] = *(const bf16x8v*)(&As[(wr * 64 + mi * 16 + lr) * 32 + lg * 8]);
        #pragma unroll
        for (int ni = 0; ni < 4; ++ni)
            bfv[ni] = *(const bf16x8v*)(&Bs[(wc * 64 + ni * 16 + lr) * 32 + lg * 8]);
        #pragma unroll
        for (int mi = 0; mi < 4; ++mi)
            #pragma unroll
            for (int ni = 0; ni < 4; ++ni)
                acc[mi][ni] = __builtin_amdgcn_mfma_f32_16x16x32_bf16(
                    af[mi], bfv[ni], acc[mi][ni], 0, 0, 0);
    }

    // Epilogue. C/D layout: col = lane&15, row = (lane>>4)*4 + reg.
    const int grow0 = m0 + wr * 64 + lg * 4;
    const int gcol0 = n0 + wc * 64 + lr;
    if (EPI == 0 && n0 >= 2 * DM) {
        // V block -> vt[bh][dk][s] (4 consecutive s per u16x4)
        #pragma unroll
        for (int mi = 0; mi < 4; ++mi) {
            const int grow = grow0 + mi * 16;
            const int b    = grow >> 11;         // / S_LEN
            const int sl   = grow & (S_LEN - 1);
            #pragma unroll
            for (int ni = 0; ni < 4; ++ni) {
                const int gcol = gcol0 + ni * 16;
                const float bv = bias[gcol];
                const int dc = gcol - 2 * DM;    // h*64 + dk
                u16x4 st;
                #pragma unroll
                for (int r = 0; r < 4; ++r) st[r] = f2bf(acc[mi][ni][r] + bv);
                *(u16x4*)(vt + ((size_t)b * NH * DKH + dc) * S_LEN + sl) = st;
            }
        }
        return;
    }
    #pragma unroll
    for (int mi = 0; mi < 4; ++mi)
        #pragma unroll
        for (int ni = 0; ni < 4; ++ni) {
            const int gcol = gcol0 + ni * 16;
            const float bv = bias[gcol];
            #pragma unroll
            for (int r = 0; r < 4; ++r) {
                const size_t idx = (size_t)(grow0 + mi * 16 + r) * N + gcol;
                const float v = acc[mi][ni][r] + bv;
                if (EPI == 0) ((unsigned short*)Cout)[idx] = f2bf(v);
                else          ((float*)Cout)[idx] = v;
            }
        }
}

// ---------------- flash attention: 4-wave block, LDS-staged K/V, static softmax ----
// (R10 kernel, verbatim — best measured config: 58 µs.)
#define EXP_C1 0.18033688f   /* 0.125 * log2(e) : softmax temp in exp2 domain */
#define KVB 64

static __device__ __forceinline__ int swzkey(int r) { return (r ^ (r >> 3)) & 7; }

#define LDS_SUB_STEP(KsB, VsB, ks)                                                   \
do {                                                                                 \
    bf16x8v kc_[4], vc_[4];                                                          \
    _Pragma("unroll")                                                                \
    for (int s_ = 0; s_ < 4; ++s_) {                                                 \
        const int r_ = (ks) + lo;                                                    \
        kc_[s_] = *(const bf16x8v*)((KsB) + r_ * 128 +                               \
                                    (((s_ * 2 + hi) ^ swzkey(r_)) << 4));            \
    }                                                                                \
    _Pragma("unroll")                                                                \
    for (int j_ = 0; j_ < 4; ++j_) {                                                 \
        const int r_ = (j_ >> 1) * 32 + lo;                                          \
        const int cc_ = ((ks) >> 3) + (j_ & 1) * 2 + hi;                             \
        vc_[j_] = *(const bf16x8v*)((VsB) + r_ * 128 +                               \
                                    ((cc_ ^ swzkey(r_)) << 4));                      \
    }                                                                                \
    f32x16 scA = {}, scB = {};                                                       \
    __builtin_amdgcn_s_setprio(1);                                                   \
    scA = __builtin_amdgcn_mfma_f32_32x32x16_bf16(kc_[0], qf[0], scA, 0, 0, 0);      \
    scB = __builtin_amdgcn_mfma_f32_32x32x16_bf16(kc_[1], qf[1], scB, 0, 0, 0);      \
    scA = __builtin_amdgcn_mfma_f32_32x32x16_bf16(kc_[2], qf[2], scA, 0, 0, 0);      \
    scB = __builtin_amdgcn_mfma_f32_32x32x16_bf16(kc_[3], qf[3], scB, 0, 0, 0);      \
    __builtin_amdgcn_s_setprio(0);                                                   \
    f32x16 sc = scA + scB;                                                           \
    float pe_[16];                                                                   \
    _Pragma("unroll")                                                                \
    for (int r_ = 0; r_ < 16; ++r_)                                                  \
        pe_[r_] = exp2_hw(sc[r_] * EXP_C1);                                          \
    float u0_ = (pe_[0] + pe_[1]) + (pe_[2] + pe_[3]);                               \
    float u1_ = (pe_[4] + pe_[5]) + (pe_[6] + pe_[7]);                               \
    float u2_ = (pe_[8] + pe_[9]) + (pe_[10] + pe_[11]);                             \
    float u3_ = (pe_[12] + pe_[13]) + (pe_[14] + pe_[15]);                           \
    float ss_ = (u0_ + u1_) + (u2_ + u3_);                                           \
    { u32x2 sw_ = pl32swap(ubits(ss_), ubits(ss_));                                  \
      ss_ = fbits(sw_[0]) + fbits(sw_[1]); }                                         \
    lsum += ss_;                                                                     \
    uint32_t a01_ = cvtpk_bf16(pe_[0],  pe_[1]),  a23_ = cvtpk_bf16(pe_[2],  pe_[3]);  \
    uint32_t a45_ = cvtpk_bf16(pe_[4],  pe_[5]),  a67_ = cvtpk_bf16(pe_[6],  pe_[7]);  \
    uint32_t b01_ = cvtpk_bf16(pe_[8],  pe_[9]),  b23_ = cvtpk_bf16(pe_[10], pe_[11]); \
    uint32_t b45_ = cvtpk_bf16(pe_[12], pe_[13]), b67_ = cvtpk_bf16(pe_[14], pe_[15]); \
    u32x2 s0_ = pl32swap(a01_, a45_);                                                \
    u32x2 s1_ = pl32swap(a23_, a67_);                                                \
    u32x2 s2_ = pl32swap(b01_, b45_);                                                \
    u32x2 s3_ = pl32swap(b23_, b67_);                                                \
    u32x4 w0_ = { s0_[0], s1_[0], s0_[1], s1_[1] };                                  \
    u32x4 w1_ = { s2_[0], s3_[0], s2_[1], s3_[1] };                                  \
    bf16x8v pa0_ = __builtin_bit_cast(bf16x8v, w0_);                                 \
    bf16x8v pa1_ = __builtin_bit_cast(bf16x8v, w1_);                                 \
    __builtin_amdgcn_s_setprio(1);                                                   \
    acc0 = __builtin_amdgcn_mfma_f32_32x32x16_bf16(vc_[0], pa0_, acc0, 0, 0, 0);     \
    acc0 = __builtin_amdgcn_mfma_f32_32x32x16_bf16(vc_[1], pa1_, acc0, 0, 0, 0);     \
    acc1 = __builtin_amdgcn_mfma_f32_32x32x16_bf16(vc_[2], pa0_, acc1, 0, 0, 0);     \
    acc1 = __builtin_amdgcn_mfma_f32_32x32x16_bf16(vc_[3], pa1_, acc1, 0, 0, 0);     \
    __builtin_amdgcn_s_setprio(0);                                                   \
} while (0)

__global__ __launch_bounds__(256, 2) void attn_kernel(
    const unsigned short* __restrict__ QKV, const unsigned short* __restrict__ Vt,
    unsigned short* __restrict__ O)
{
    const int tid  = threadIdx.x;
    const int w    = tid >> 6;
    const int lane = tid & 63;
    const int lo = lane & 31;
    const int hi = lane >> 5;

    // T1: XCD-chunked bijective swizzle; 512 blocks = 8 XCDs x 64.
    const int flat = blockIdx.x;
    const int virt = (flat & 7) * 64 + (flat >> 3);
    const int bh = virt >> 4;          // 0..31
    const int qb = virt & 15;          // 0..15
    const int b = bh >> 4, h = bh & 15;
    const int q0 = qb * 128 + w * 32;

    __shared__ __attribute__((aligned(16))) unsigned short Ks[2][KVB * 64];
    __shared__ __attribute__((aligned(16))) unsigned short Vs[2][KVB * 64];

    const unsigned short* Kq  = QKV + (size_t)b * S_LEN * NQKV + DM + h * 64;
    const unsigned short* Vtb = Vt + (size_t)bh * DKH * S_LEN;   // [64][2048]

    const int sr  = tid >> 3, scn = tid & 7;
    const size_t kSrc0 = (size_t)sr * NQKV + ((scn ^ swzkey(sr)) * 8);
    const size_t kSrc1 = (size_t)(sr + 32) * NQKV + ((scn ^ swzkey(sr + 32)) * 8);
    const size_t vSrc0 = (size_t)sr * S_LEN + ((scn ^ swzkey(sr)) * 8);
    const size_t vSrc1 = (size_t)(sr + 32) * S_LEN + ((scn ^ swzkey(sr + 32)) * 8);
    const int dstOff0 = (tid & ~63) * 16;
    const int dstOff1 = dstOff0 + 4096;

#define STAGE_TILE(buf, kvOff)                                                        \
    do {                                                                              \
        __builtin_amdgcn_global_load_lds((gas_void*)(Kq + (kvOff) * NQKV + kSrc0),    \
            (las_void*)((char*)&Ks[buf][0] + dstOff0), 16, 0, 0);                     \
        __builtin_amdgcn_global_load_lds((gas_void*)(Kq + (kvOff) * NQKV + kSrc1),    \
            (las_void*)((char*)&Ks[buf][0] + dstOff1), 16, 0, 0);                     \
        __builtin_amdgcn_global_load_lds((gas_void*)(Vtb + (kvOff) + vSrc0),          \
            (las_void*)((char*)&Vs[buf][0] + dstOff0), 16, 0, 0);                     \
        __builtin_amdgcn_global_load_lds((gas_void*)(Vtb + (kvOff) + vSrc1),          \
            (las_void*)((char*)&Vs[buf][0] + dstOff1), 16, 0, 0);                     \
    } while (0)

    const unsigned short* Qp =
        QKV + ((size_t)b * S_LEN + q0 + lo) * NQKV + h * 64 + hi * 8;
    bf16x8v qf[4];
    #pragma unroll
    for (int s = 0; s < 4; ++s) qf[s] = *(const bf16x8v*)(Qp + s * 16);

    f32x16 acc0 = {}, acc1 = {};
    float lsum = 0.f;

    STAGE_TILE(0, (size_t)0);
    __syncthreads();

    int cur = 0;
    for (int t = 0; t < S_LEN / KVB; ++t) {
        const int nxt = cur ^ 1;
        if (t + 1 < S_LEN / KVB) STAGE_TILE(nxt, (size_t)(t + 1) * KVB);
        const char* KsB = (const char*)&Ks[cur][0];
        const char* VsB = (const char*)&Vs[cur][0];
        LDS_SUB_STEP(KsB, VsB, 0);
        LDS_SUB_STEP(KsB, VsB, 32);
        __syncthreads();
        cur = nxt;
    }
#undef STAGE_TILE

    const float linv = 1.f / lsum;
    unsigned short* Orow = O + ((size_t)b * S_LEN + q0 + lo) * DM + h * 64 + hi * 4;
    #pragma unroll
    for (int g = 0; g < 4; ++g) {
        u16x4 st0, st1;
        #pragma unroll
        for (int k2 = 0; k2 < 4; ++k2) {
            st0[k2] = f2bf(acc0[g * 4 + k2] * linv);
            st1[k2] = f2bf(acc1[g * 4 + k2] * linv);
        }
        *(u16x4*)(Orow + g * 8)      = st0;
        *(u16x4*)(Orow + 32 + g * 8) = st1;
    }
}

// ---------------- host launcher ----------------
extern "C" void kernel_launch(void* const* d_in, const int* in_sizes, int n_in,
                              void* d_out, int out_size, void* d_ws, size_t ws_size,
                              hipStream_t stream)
{
    const float* x    = (const float*)d_in[0];
    const float* Wqkv = (const float*)d_in[1];
    const float* bqkv = (const float*)d_in[2];
    const float* Wout = (const float*)d_in[3];
    const float* bout = (const float*)d_in[4];
    float* out = (float*)d_out;

    char* ws = (char*)d_ws;
    // layout (bytes):
    //  [0,         8388608)  xb (x bf16; dead after QKV GEMM)
    //  [8388608,  14680064)  wqkv_t bf16 [3072][1024]
    //  [14680064, 16777216)  wout_t bf16 [1024][1024]
    //  [16777216, 41943040)  qkvb bf16 [4096][3072]  (V region never written/read)
    //  [41943040, 50331648)  attn_o bf16 [4096][1024]
    //  [50331648, 58720256)  vtb bf16 [32][64][2048] (written by gemm<0> epilogue)
    unsigned short* xb     = (unsigned short*)(ws);
    unsigned short* wqkv_t = (unsigned short*)(ws + 8388608);
    unsigned short* wout_t = (unsigned short*)(ws + 14680064);
    unsigned short* qkvb   = (unsigned short*)(ws + 16777216);
    unsigned short* attn_o = (unsigned short*)(ws + 41943040);
    unsigned short* vtb    = (unsigned short*)(ws + 50331648);

    prep_kernel<<<6144, 256, 0, stream>>>(x, xb, Wqkv, wqkv_t, Wout, wout_t);
    gemm_bt_kernel<0><<<dim3(NQKV / 128, M_ROWS / 128), 256, 0, stream>>>(
        xb, wqkv_t, bqkv, (void*)qkvb, vtb, M_ROWS, NQKV, DM);
    attn_kernel<<<512, 256, 0, stream>>>(qkvb, vtb, attn_o);
    gemm_bt_kernel<1><<<dim3(DM / 128, M_ROWS / 128), 256, 0, stream>>>(
        attn_o, wout_t, bout, (void*)out, nullptr, M_ROWS, DM, DM);
}

// Round 13
// 133.472 us; speedup vs baseline: 1.0512x; 1.0144x over previous
//
#include <hip/hip_runtime.h>
#include <hip/hip_bf16.h>
#include <stdint.h>

// Problem constants
#define S_LEN 2048
#define DM    1024
#define NH    16
#define DKH   64
#define BATCH 2
#define M_ROWS (BATCH * S_LEN)   // 4096
#define NQKV   (3 * DM)          // 3072

typedef short          bf16x8v __attribute__((ext_vector_type(8)));
typedef float          f32x4   __attribute__((ext_vector_type(4)));
typedef float          f32x16  __attribute__((ext_vector_type(16)));
typedef unsigned short u16x4   __attribute__((ext_vector_type(4)));
typedef unsigned short u16x8   __attribute__((ext_vector_type(8)));
typedef unsigned int   u32x2   __attribute__((ext_vector_type(2)));
typedef unsigned int   u32x4   __attribute__((ext_vector_type(4)));

typedef const void __attribute__((address_space(1))) gas_void;
typedef void       __attribute__((address_space(3))) las_void;

static __device__ __forceinline__ unsigned short f2bf(float f) {
    union { float f; uint32_t u; } v; v.f = f;
    uint32_t u = v.u;
    uint32_t r = (u + 0x7fffu + ((u >> 16) & 1u)) >> 16;  // RNE
    return (unsigned short)r;
}

// raw v_exp_f32: D = 2^S0
static __device__ __forceinline__ float exp2_hw(float x) {
    float r;
    asm("v_exp_f32 %0, %1" : "=v"(r) : "v"(x));
    return r;
}

// pack 2 f32 -> 2 bf16 in one u32 (lo = first arg)
static __device__ __forceinline__ uint32_t cvtpk_bf16(float lo, float hi) {
    uint32_t r;
    asm("v_cvt_pk_bf16_f32 %0, %1, %2" : "=v"(r) : "v"(lo), "v"(hi));
    return r;
}
// swap: new_a = {a[0:31], b[0:31]}, new_b = {a[32:63], b[32:63]}
static __device__ __forceinline__ u32x2 pl32swap(uint32_t a, uint32_t b) {
    return __builtin_amdgcn_permlane32_swap(a, b, false, false);
}
static __device__ __forceinline__ float    fbits(uint32_t u) { return __builtin_bit_cast(float, u); }
static __device__ __forceinline__ uint32_t ubits(float f)    { return __builtin_bit_cast(uint32_t, f); }

// ---------------- fused prep: x->bf16 + W transposes (3 kernels in 1) ----------
// blocks [0,2048): cvt x; [2048,5120): transpose Wqkv; [5120,6144): transpose Wout.
__global__ __launch_bounds__(256) void prep_kernel(
    const float* __restrict__ x, unsigned short* __restrict__ xb,
    const float* __restrict__ Wqkv, unsigned short* __restrict__ wqkv_t,
    const float* __restrict__ Wout, unsigned short* __restrict__ wout_t)
{
    const int bid = blockIdx.x;
    const int tid = threadIdx.x;
    __shared__ float t[32][33];

    if (bid < 2048) {
        const int i = bid * 256 + tid;
        f32x4 a = *(const f32x4*)(x + (size_t)i * 8);
        f32x4 b = *(const f32x4*)(x + (size_t)i * 8 + 4);
        u16x8 o;
        #pragma unroll
        for (int j = 0; j < 4; ++j) { o[j] = f2bf(a[j]); o[4 + j] = f2bf(b[j]); }
        *(u16x8*)(xb + (size_t)i * 8) = o;
        return;
    }
    const float* W; unsigned short* Wt; int N, tb;
    if (bid < 2048 + 3072) { W = Wqkv; Wt = wqkv_t; N = NQKV; tb = bid - 2048; }
    else                   { W = Wout; Wt = wout_t; N = DM;   tb = bid - 5120; }
    const int K  = DM;
    const int nb = N / 32;
    const int n0 = (tb % nb) * 32, k0 = (tb / nb) * 32;
    const int tx = tid & 31, ty = tid >> 5;
    #pragma unroll
    for (int i = 0; i < 4; ++i)
        t[ty * 4 + i][tx] = W[(size_t)(k0 + ty * 4 + i) * N + n0 + tx];
    __syncthreads();
    #pragma unroll
    for (int i = 0; i < 4; ++i)
        Wt[(size_t)(n0 + ty * 4 + i) * K + k0 + tx] = f2bf(t[tx][ty * 4 + i]);
}

// ---------------- GEMM: C[M][N] = A[M][K] * Bt[N][K]^T + bias ----------------
// EPI==0: bf16 output; V-region blocks (n0 >= 2*DM, qkv only) write TRANSPOSED
// into vt[bh][dk][s] via an LDS transpose (coalesced 128B store runs).
// EPI==1: fp32 output.
template <int EPI>
__global__ __launch_bounds__(256) void gemm_bt_kernel(
    const unsigned short* __restrict__ A, const unsigned short* __restrict__ Bt,
    const float* __restrict__ bias, void* __restrict__ Cout,
    unsigned short* __restrict__ vt,
    int M, int N, int K)
{
    // single 16 KB pool: As = [0,4096) u16, Bs = [4096,8192) u16.
    // After the K-loop it is reused as the V-transpose buffer tileT[128][64].
    __shared__ __attribute__((aligned(16))) unsigned short smem[2 * 128 * 32];
    unsigned short* As = smem;
    unsigned short* Bs = smem + 128 * 32;

    const int tid  = threadIdx.x;
    const int lane = tid & 63;
    const int w    = tid >> 6;
    const int wr   = w >> 1, wc = w & 1;
    const int lr   = lane & 15, lg = lane >> 4;
    const int m0   = blockIdx.y * 128, n0 = blockIdx.x * 128;

    f32x4 acc[4][4];
    #pragma unroll
    for (int i = 0; i < 4; ++i)
        #pragma unroll
        for (int j = 0; j < 4; ++j) acc[i][j] = (f32x4){0.f, 0.f, 0.f, 0.f};

    for (int kt = 0; kt < K; kt += 32) {
        if (kt) __syncthreads();
        #pragma unroll
        for (int j = 0; j < 2; ++j) {
            const int c  = j * 256 + tid;
            const int r  = c >> 2;
            const int kc = (c & 3) * 8;
            const int cb = j * 256 + (tid & ~63);
            __builtin_amdgcn_global_load_lds(
                (gas_void*)(A + (size_t)(m0 + r) * K + kt + kc),
                (las_void*)((char*)As + (size_t)cb * 16), 16, 0, 0);
            __builtin_amdgcn_global_load_lds(
                (gas_void*)(Bt + (size_t)(n0 + r) * K + kt + kc),
                (las_void*)((char*)Bs + (size_t)cb * 16), 16, 0, 0);
        }
        __syncthreads();

        bf16x8v af[4], bfv[4];
        #pragma unroll
        for (int mi = 0; mi < 4; ++mi)
            af[mi] = *(const bf16x8v*)(&As[(wr * 64 + mi * 16 + lr) * 32 + lg * 8]);
        #pragma unroll
        for (int ni = 0; ni < 4; ++ni)
            bfv[ni] = *(const bf16x8v*)(&Bs[(wc * 64 + ni * 16 + lr) * 32 + lg * 8]);
        #pragma unroll
        for (int mi = 0; mi < 4; ++mi)
            #pragma unroll
            for (int ni = 0; ni < 4; ++ni)
                acc[mi][ni] = __builtin_amdgcn_mfma_f32_16x16x32_bf16(
                    af[mi], bfv[ni], acc[mi][ni], 0, 0, 0);
    }

    // Epilogue. C/D layout: col = lane&15, row = (lane>>4)*4 + reg.
    const int grow0 = m0 + wr * 64 + lg * 4;
    const int gcol0 = n0 + wc * 64 + lr;
    if (EPI == 0 && n0 >= 2 * DM) {
        // V block -> vt[bh][dk][s] via LDS transpose: 2 passes of 64 s-rows.
        // tileT[d][s_half] (128x64 u16 = 16 KB), XOR swizzle s ^= (d&7)<<3.
        const int b = m0 >> 11;                    // batch of this block's rows
        const int sg = m0 & (S_LEN - 1);           // s base within batch
        unsigned short* tileT = smem;
        #pragma unroll
        for (int p = 0; p < 2; ++p) {
            __syncthreads();                       // As/Bs (or prev pass) dead
            if (wr == p) {
                #pragma unroll
                for (int mi = 0; mi < 4; ++mi)
                    #pragma unroll
                    for (int ni = 0; ni < 4; ++ni) {
                        const int d_local = wc * 64 + ni * 16 + lr;   // 0..127
                        const float bv = bias[n0 + d_local];
                        u16x4 st;
                        #pragma unroll
                        for (int r = 0; r < 4; ++r) st[r] = f2bf(acc[mi][ni][r] + bv);
                        const int sb = mi * 16 + lg * 4;              // 0..60
                        *(u16x4*)&tileT[d_local * 64 + (sb ^ ((d_local & 7) << 3))] = st;
                    }
            }
            __syncthreads();
            #pragma unroll
            for (int i = 0; i < 4; ++i) {
                const int cid = i * 256 + tid;     // 0..1023
                const int dr  = cid >> 3;          // d row 0..127
                const int c   = cid & 7;           // 16B chunk in row
                u16x8 v = *(const u16x8*)&tileT[dr * 64 + ((c * 8) ^ ((dr & 7) << 3))];
                *(u16x8*)(vt + ((size_t)b * NH * DKH + (n0 - 2 * DM) + dr) * S_LEN
                              + sg + p * 64 + c * 8) = v;
            }
        }
        return;
    }
    #pragma unroll
    for (int mi = 0; mi < 4; ++mi)
        #pragma unroll
        for (int ni = 0; ni < 4; ++ni) {
            const int gcol = gcol0 + ni * 16;
            const float bv = bias[gcol];
            #pragma unroll
            for (int r = 0; r < 4; ++r) {
                const size_t idx = (size_t)(grow0 + mi * 16 + r) * N + gcol;
                const float v = acc[mi][ni][r] + bv;
                if (EPI == 0) ((unsigned short*)Cout)[idx] = f2bf(v);
                else          ((float*)Cout)[idx] = v;
            }
        }
}

// ---------------- flash attention: 4-wave block, LDS-staged K/V, static softmax ----
// (R10 kernel, verbatim — best measured config: 58 µs.)
#define EXP_C1 0.18033688f   /* 0.125 * log2(e) : softmax temp in exp2 domain */
#define KVB 64

static __device__ __forceinline__ int swzkey(int r) { return (r ^ (r >> 3)) & 7; }

#define LDS_SUB_STEP(KsB, VsB, ks)                                                   \
do {                                                                                 \
    bf16x8v kc_[4], vc_[4];                                                          \
    _Pragma("unroll")                                                                \
    for (int s_ = 0; s_ < 4; ++s_) {                                                 \
        const int r_ = (ks) + lo;                                                    \
        kc_[s_] = *(const bf16x8v*)((KsB) + r_ * 128 +                               \
                                    (((s_ * 2 + hi) ^ swzkey(r_)) << 4));            \
    }                                                                                \
    _Pragma("unroll")                                                                \
    for (int j_ = 0; j_ < 4; ++j_) {                                                 \
        const int r_ = (j_ >> 1) * 32 + lo;                                          \
        const int cc_ = ((ks) >> 3) + (j_ & 1) * 2 + hi;                             \
        vc_[j_] = *(const bf16x8v*)((VsB) + r_ * 128 +                               \
                                    ((cc_ ^ swzkey(r_)) << 4));                      \
    }                                                                                \
    f32x16 scA = {}, scB = {};                                                       \
    __builtin_amdgcn_s_setprio(1);                                                   \
    scA = __builtin_amdgcn_mfma_f32_32x32x16_bf16(kc_[0], qf[0], scA, 0, 0, 0);      \
    scB = __builtin_amdgcn_mfma_f32_32x32x16_bf16(kc_[1], qf[1], scB, 0, 0, 0);      \
    scA = __builtin_amdgcn_mfma_f32_32x32x16_bf16(kc_[2], qf[2], scA, 0, 0, 0);      \
    scB = __builtin_amdgcn_mfma_f32_32x32x16_bf16(kc_[3], qf[3], scB, 0, 0, 0);      \
    __builtin_amdgcn_s_setprio(0);                                                   \
    f32x16 sc = scA + scB;                                                           \
    float pe_[16];                                                                   \
    _Pragma("unroll")                                                                \
    for (int r_ = 0; r_ < 16; ++r_)                                                  \
        pe_[r_] = exp2_hw(sc[r_] * EXP_C1);                                          \
    float u0_ = (pe_[0] + pe_[1]) + (pe_[2] + pe_[3]);                               \
    float u1_ = (pe_[4] + pe_[5]) + (pe_[6] + pe_[7]);                               \
    float u2_ = (pe_[8] + pe_[9]) + (pe_[10] + pe_[11]);                             \
    float u3_ = (pe_[12] + pe_[13]) + (pe_[14] + pe_[15]);                           \
    float ss_ = (u0_ + u1_) + (u2_ + u3_);                                           \
    { u32x2 sw_ = pl32swap(ubits(ss_), ubits(ss_));                                  \
      ss_ = fbits(sw_[0]) + fbits(sw_[1]); }                                         \
    lsum += ss_;                                                                     \
    uint32_t a01_ = cvtpk_bf16(pe_[0],  pe_[1]),  a23_ = cvtpk_bf16(pe_[2],  pe_[3]);  \
    uint32_t a45_ = cvtpk_bf16(pe_[4],  pe_[5]),  a67_ = cvtpk_bf16(pe_[6],  pe_[7]);  \
    uint32_t b01_ = cvtpk_bf16(pe_[8],  pe_[9]),  b23_ = cvtpk_bf16(pe_[10], pe_[11]); \
    uint32_t b45_ = cvtpk_bf16(pe_[12], pe_[13]), b67_ = cvtpk_bf16(pe_[14], pe_[15]); \
    u32x2 s0_ = pl32swap(a01_, a45_);                                                \
    u32x2 s1_ = pl32swap(a23_, a67_);                                                \
    u32x2 s2_ = pl32swap(b01_, b45_);                                                \
    u32x2 s3_ = pl32swap(b23_, b67_);                                                \
    u32x4 w0_ = { s0_[0], s1_[0], s0_[1], s1_[1] };                                  \
    u32x4 w1_ = { s2_[0], s3_[0], s2_[1], s3_[1] };                                  \
    bf16x8v pa0_ = __builtin_bit_cast(bf16x8v, w0_);                                 \
    bf16x8v pa1_ = __builtin_bit_cast(bf16x8v, w1_);                                 \
    __builtin_amdgcn_s_setprio(1);                                                   \
    acc0 = __builtin_amdgcn_mfma_f32_32x32x16_bf16(vc_[0], pa0_, acc0, 0, 0, 0);     \
    acc0 = __builtin_amdgcn_mfma_f32_32x32x16_bf16(vc_[1], pa1_, acc0, 0, 0, 0);     \
    acc1 = __builtin_amdgcn_mfma_f32_32x32x16_bf16(vc_[2], pa0_, acc1, 0, 0, 0);     \
    acc1 = __builtin_amdgcn_mfma_f32_32x32x16_bf16(vc_[3], pa1_, acc1, 0, 0, 0);     \
    __builtin_amdgcn_s_setprio(0);                                                   \
} while (0)

__global__ __launch_bounds__(256, 2) void attn_kernel(
    const unsigned short* __restrict__ QKV, const unsigned short* __restrict__ Vt,
    unsigned short* __restrict__ O)
{
    const int tid  = threadIdx.x;
    const int w    = tid >> 6;
    const int lane = tid & 63;
    const int lo = lane & 31;
    const int hi = lane >> 5;

    // T1: XCD-chunked bijective swizzle; 512 blocks = 8 XCDs x 64.
    const int flat = blockIdx.x;
    const int virt = (flat & 7) * 64 + (flat >> 3);
    const int bh = virt >> 4;          // 0..31
    const int qb = virt & 15;          // 0..15
    const int b = bh >> 4, h = bh & 15;
    const int q0 = qb * 128 + w * 32;

    __shared__ __attribute__((aligned(16))) unsigned short Ks[2][KVB * 64];
    __shared__ __attribute__((aligned(16))) unsigned short Vs[2][KVB * 64];

    const unsigned short* Kq  = QKV + (size_t)b * S_LEN * NQKV + DM + h * 64;
    const unsigned short* Vtb = Vt + (size_t)bh * DKH * S_LEN;   // [64][2048]

    const int sr  = tid >> 3, scn = tid & 7;
    const size_t kSrc0 = (size_t)sr * NQKV + ((scn ^ swzkey(sr)) * 8);
    const size_t kSrc1 = (size_t)(sr + 32) * NQKV + ((scn ^ swzkey(sr + 32)) * 8);
    const size_t vSrc0 = (size_t)sr * S_LEN + ((scn ^ swzkey(sr)) * 8);
    const size_t vSrc1 = (size_t)(sr + 32) * S_LEN + ((scn ^ swzkey(sr + 32)) * 8);
    const int dstOff0 = (tid & ~63) * 16;
    const int dstOff1 = dstOff0 + 4096;

#define STAGE_TILE(buf, kvOff)                                                        \
    do {                                                                              \
        __builtin_amdgcn_global_load_lds((gas_void*)(Kq + (kvOff) * NQKV + kSrc0),    \
            (las_void*)((char*)&Ks[buf][0] + dstOff0), 16, 0, 0);                     \
        __builtin_amdgcn_global_load_lds((gas_void*)(Kq + (kvOff) * NQKV + kSrc1),    \
            (las_void*)((char*)&Ks[buf][0] + dstOff1), 16, 0, 0);                     \
        __builtin_amdgcn_global_load_lds((gas_void*)(Vtb + (kvOff) + vSrc0),          \
            (las_void*)((char*)&Vs[buf][0] + dstOff0), 16, 0, 0);                     \
        __builtin_amdgcn_global_load_lds((gas_void*)(Vtb + (kvOff) + vSrc1),          \
            (las_void*)((char*)&Vs[buf][0] + dstOff1), 16, 0, 0);                     \
    } while (0)

    const unsigned short* Qp =
        QKV + ((size_t)b * S_LEN + q0 + lo) * NQKV + h * 64 + hi * 8;
    bf16x8v qf[4];
    #pragma unroll
    for (int s = 0; s < 4; ++s) qf[s] = *(const bf16x8v*)(Qp + s * 16);

    f32x16 acc0 = {}, acc1 = {};
    float lsum = 0.f;

    STAGE_TILE(0, (size_t)0);
    __syncthreads();

    int cur = 0;
    for (int t = 0; t < S_LEN / KVB; ++t) {
        const int nxt = cur ^ 1;
        if (t + 1 < S_LEN / KVB) STAGE_TILE(nxt, (size_t)(t + 1) * KVB);
        const char* KsB = (const char*)&Ks[cur][0];
        const char* VsB = (const char*)&Vs[cur][0];
        LDS_SUB_STEP(KsB, VsB, 0);
        LDS_SUB_STEP(KsB, VsB, 32);
        __syncthreads();
        cur = nxt;
    }
#undef STAGE_TILE

    const float linv = 1.f / lsum;
    unsigned short* Orow = O + ((size_t)b * S_LEN + q0 + lo) * DM + h * 64 + hi * 4;
    #pragma unroll
    for (int g = 0; g < 4; ++g) {
        u16x4 st0, st1;
        #pragma unroll
        for (int k2 = 0; k2 < 4; ++k2) {
            st0[k2] = f2bf(acc0[g * 4 + k2] * linv);
            st1[k2] = f2bf(acc1[g * 4 + k2] * linv);
        }
        *(u16x4*)(Orow + g * 8)      = st0;
        *(u16x4*)(Orow + 32 + g * 8) = st1;
    }
}

// ---------------- host launcher ----------------
extern "C" void kernel_launch(void* const* d_in, const int* in_sizes, int n_in,
                              void* d_out, int out_size, void* d_ws, size_t ws_size,
                              hipStream_t stream)
{
    const float* x    = (const float*)d_in[0];
    const float* Wqkv = (const float*)d_in[1];
    const float* bqkv = (const float*)d_in[2];
    const float* Wout = (const float*)d_in[3];
    const float* bout = (const float*)d_in[4];
    float* out = (float*)d_out;

    char* ws = (char*)d_ws;
    // layout (bytes):
    //  [0,         8388608)  xb (x bf16; dead after QKV GEMM)
    //  [8388608,  14680064)  wqkv_t bf16 [3072][1024]
    //  [14680064, 16777216)  wout_t bf16 [1024][1024]
    //  [16777216, 41943040)  qkvb bf16 [4096][3072]  (V region never written/read)
    //  [41943040, 50331648)  attn_o bf16 [4096][1024]
    //  [50331648, 58720256)  vtb bf16 [32][64][2048] (written by gemm<0> epilogue)
    unsigned short* xb     = (unsigned short*)(ws);
    unsigned short* wqkv_t = (unsigned short*)(ws + 8388608);
    unsigned short* wout_t = (unsigned short*)(ws + 14680064);
    unsigned short* qkvb   = (unsigned short*)(ws + 16777216);
    unsigned short* attn_o = (unsigned short*)(ws + 41943040);
    unsigned short* vtb    = (unsigned short*)(ws + 50331648);

    prep_kernel<<<6144, 256, 0, stream>>>(x, xb, Wqkv, wqkv_t, Wout, wout_t);
    gemm_bt_kernel<0><<<dim3(NQKV / 128, M_ROWS / 128), 256, 0, stream>>>(
        xb, wqkv_t, bqkv, (void*)qkvb, vtb, M_ROWS, NQKV, DM);
    attn_kernel<<<512, 256, 0, stream>>>(qkvb, vtb, attn_o);
    gemm_bt_kernel<1><<<dim3(DM / 128, M_ROWS / 128), 256, 0, stream>>>(
        attn_o, wout_t, bout, (void*)out, nullptr, M_ROWS, DM, DM);
}

// Round 14
// 125.760 us; speedup vs baseline: 1.1156x; 1.0613x over previous
//
#include <hip/hip_runtime.h>
#include <hip/hip_bf16.h>
#include <stdint.h>

// Problem constants
#define S_LEN 2048
#define DM    1024
#define NH    16
#define DKH   64
#define BATCH 2
#define M_ROWS (BATCH * S_LEN)   // 4096
#define NQKV   (3 * DM)          // 3072

typedef short          bf16x8v __attribute__((ext_vector_type(8)));
typedef float          f32x4   __attribute__((ext_vector_type(4)));
typedef float          f32x16  __attribute__((ext_vector_type(16)));
typedef unsigned short u16x4   __attribute__((ext_vector_type(4)));
typedef unsigned short u16x8   __attribute__((ext_vector_type(8)));
typedef unsigned int   u32x2   __attribute__((ext_vector_type(2)));
typedef unsigned int   u32x4   __attribute__((ext_vector_type(4)));

typedef const void __attribute__((address_space(1))) gas_void;
typedef void       __attribute__((address_space(3))) las_void;

static __device__ __forceinline__ unsigned short f2bf(float f) {
    union { float f; uint32_t u; } v; v.f = f;
    uint32_t u = v.u;
    uint32_t r = (u + 0x7fffu + ((u >> 16) & 1u)) >> 16;  // RNE
    return (unsigned short)r;
}

// raw v_exp_f32: D = 2^S0
static __device__ __forceinline__ float exp2_hw(float x) {
    float r;
    asm("v_exp_f32 %0, %1" : "=v"(r) : "v"(x));
    return r;
}

// pack 2 f32 -> 2 bf16 in one u32 (lo = first arg)
static __device__ __forceinline__ uint32_t cvtpk_bf16(float lo, float hi) {
    uint32_t r;
    asm("v_cvt_pk_bf16_f32 %0, %1, %2" : "=v"(r) : "v"(lo), "v"(hi));
    return r;
}
// swap: new_a = {a[0:31], b[0:31]}, new_b = {a[32:63], b[32:63]}
static __device__ __forceinline__ u32x2 pl32swap(uint32_t a, uint32_t b) {
    return __builtin_amdgcn_permlane32_swap(a, b, false, false);
}
static __device__ __forceinline__ float    fbits(uint32_t u) { return __builtin_bit_cast(float, u); }
static __device__ __forceinline__ uint32_t ubits(float f)    { return __builtin_bit_cast(uint32_t, f); }

// ---------------- fused prep: x->bf16 + W transposes (3 kernels in 1) ----------
// blocks [0,2048): cvt x; [2048,5120): transpose Wqkv; [5120,6144): transpose Wout.
__global__ __launch_bounds__(256) void prep_kernel(
    const float* __restrict__ x, unsigned short* __restrict__ xb,
    const float* __restrict__ Wqkv, unsigned short* __restrict__ wqkv_t,
    const float* __restrict__ Wout, unsigned short* __restrict__ wout_t)
{
    const int bid = blockIdx.x;
    const int tid = threadIdx.x;
    __shared__ float t[32][33];

    if (bid < 2048) {
        const int i = bid * 256 + tid;
        f32x4 a = *(const f32x4*)(x + (size_t)i * 8);
        f32x4 b = *(const f32x4*)(x + (size_t)i * 8 + 4);
        u16x8 o;
        #pragma unroll
        for (int j = 0; j < 4; ++j) { o[j] = f2bf(a[j]); o[4 + j] = f2bf(b[j]); }
        *(u16x8*)(xb + (size_t)i * 8) = o;
        return;
    }
    const float* W; unsigned short* Wt; int N, tb;
    if (bid < 2048 + 3072) { W = Wqkv; Wt = wqkv_t; N = NQKV; tb = bid - 2048; }
    else                   { W = Wout; Wt = wout_t; N = DM;   tb = bid - 5120; }
    const int K  = DM;
    const int nb = N / 32;
    const int n0 = (tb % nb) * 32, k0 = (tb / nb) * 32;
    const int tx = tid & 31, ty = tid >> 5;
    #pragma unroll
    for (int i = 0; i < 4; ++i)
        t[ty * 4 + i][tx] = W[(size_t)(k0 + ty * 4 + i) * N + n0 + tx];
    __syncthreads();
    #pragma unroll
    for (int i = 0; i < 4; ++i)
        Wt[(size_t)(n0 + ty * 4 + i) * K + k0 + tx] = f2bf(t[tx][ty * 4 + i]);
}

// ---------------- GEMM: C[M][N] = A[M][K] * Bt[N][K]^T + bias ----------------
// (R10-verbatim: no V fusion.) EPI==0: bf16 out; EPI==1: fp32 out.
template <int EPI>
__global__ __launch_bounds__(256) void gemm_bt_kernel(
    const unsigned short* __restrict__ A, const unsigned short* __restrict__ Bt,
    const float* __restrict__ bias, void* __restrict__ Cout,
    int M, int N, int K)
{
    __shared__ __attribute__((aligned(16))) unsigned short As[128 * 32];
    __shared__ __attribute__((aligned(16))) unsigned short Bs[128 * 32];

    const int tid  = threadIdx.x;
    const int lane = tid & 63;
    const int w    = tid >> 6;
    const int wr   = w >> 1, wc = w & 1;
    const int lr   = lane & 15, lg = lane >> 4;
    const int m0   = blockIdx.y * 128, n0 = blockIdx.x * 128;

    f32x4 acc[4][4];
    #pragma unroll
    for (int i = 0; i < 4; ++i)
        #pragma unroll
        for (int j = 0; j < 4; ++j) acc[i][j] = (f32x4){0.f, 0.f, 0.f, 0.f};

    for (int kt = 0; kt < K; kt += 32) {
        if (kt) __syncthreads();
        #pragma unroll
        for (int j = 0; j < 2; ++j) {
            const int c  = j * 256 + tid;
            const int r  = c >> 2;
            const int kc = (c & 3) * 8;
            const int cb = j * 256 + (tid & ~63);
            __builtin_amdgcn_global_load_lds(
                (gas_void*)(A + (size_t)(m0 + r) * K + kt + kc),
                (las_void*)((char*)As + (size_t)cb * 16), 16, 0, 0);
            __builtin_amdgcn_global_load_lds(
                (gas_void*)(Bt + (size_t)(n0 + r) * K + kt + kc),
                (las_void*)((char*)Bs + (size_t)cb * 16), 16, 0, 0);
        }
        __syncthreads();

        bf16x8v af[4], bfv[4];
        #pragma unroll
        for (int mi = 0; mi < 4; ++mi)
            af[mi] = *(const bf16x8v*)(&As[(wr * 64 + mi * 16 + lr) * 32 + lg * 8]);
        #pragma unroll
        for (int ni = 0; ni < 4; ++ni)
            bfv[ni] = *(const bf16x8v*)(&Bs[(wc * 64 + ni * 16 + lr) * 32 + lg * 8]);
        #pragma unroll
        for (int mi = 0; mi < 4; ++mi)
            #pragma unroll
            for (int ni = 0; ni < 4; ++ni)
                acc[mi][ni] = __builtin_amdgcn_mfma_f32_16x16x32_bf16(
                    af[mi], bfv[ni], acc[mi][ni], 0, 0, 0);
    }

    const int grow0 = m0 + wr * 64 + lg * 4;
    const int gcol0 = n0 + wc * 64 + lr;
    #pragma unroll
    for (int mi = 0; mi < 4; ++mi)
        #pragma unroll
        for (int ni = 0; ni < 4; ++ni) {
            const int gcol = gcol0 + ni * 16;
            const float bv = bias[gcol];
            #pragma unroll
            for (int r = 0; r < 4; ++r) {
                const size_t idx = (size_t)(grow0 + mi * 16 + r) * N + gcol;
                const float v = acc[mi][ni][r] + bv;
                if (EPI == 0) ((unsigned short*)Cout)[idx] = f2bf(v);
                else          ((float*)Cout)[idx] = v;
            }
        }
}

// ---------------- split V only: qkv V-block -> Vt [bh][64][s] (R10-verbatim) ----
__global__ __launch_bounds__(256) void split_v_kernel(
    const unsigned short* __restrict__ qkv, unsigned short* __restrict__ vt)
{
    const int tid = threadIdx.x;
    const int bh  = blockIdx.y;
    const int h   = bh & 15;
    const int b   = bh >> 4;
    const int s0  = blockIdx.x * 64;
    __shared__ __attribute__((aligned(16))) unsigned short tile[64][68];

    #pragma unroll
    for (int j = 0; j < 4; ++j) {
        const int c  = tid + j * 256;      // 0..1023 (chunks of 4 ushorts)
        const int r  = c >> 4;             // s row 0..63
        const int c4 = (c & 15) * 4;       // dk col 0..60
        const size_t srow = ((size_t)b * S_LEN + s0 + r) * NQKV + 2 * DM + h * 64 + c4;
        *(u16x4*)&tile[r][c4] = *(const u16x4*)(qkv + srow);
    }
    __syncthreads();
    #pragma unroll
    for (int j = 0; j < 4; ++j) {
        const int c   = tid + j * 256;
        const int dkr = c >> 4;            // dk row of Vt
        const int s4  = (c & 15) * 4;      // s col
        u16x4 o;
        #pragma unroll
        for (int i = 0; i < 4; ++i) o[i] = tile[s4 + i][dkr];
        *(u16x4*)(vt + ((size_t)bh * DKH + dkr) * S_LEN + s0 + s4) = o;
    }
}

// ---------------- flash attention: 4-wave block, LDS-staged K/V, static softmax ----
// (R10 kernel, verbatim — best measured config: 58 µs.)
#define EXP_C1 0.18033688f   /* 0.125 * log2(e) : softmax temp in exp2 domain */
#define KVB 64

static __device__ __forceinline__ int swzkey(int r) { return (r ^ (r >> 3)) & 7; }

#define LDS_SUB_STEP(KsB, VsB, ks)                                                   \
do {                                                                                 \
    bf16x8v kc_[4], vc_[4];                                                          \
    _Pragma("unroll")                                                                \
    for (int s_ = 0; s_ < 4; ++s_) {                                                 \
        const int r_ = (ks) + lo;                                                    \
        kc_[s_] = *(const bf16x8v*)((KsB) + r_ * 128 +                               \
                                    (((s_ * 2 + hi) ^ swzkey(r_)) << 4));            \
    }                                                                                \
    _Pragma("unroll")                                                                \
    for (int j_ = 0; j_ < 4; ++j_) {                                                 \
        const int r_ = (j_ >> 1) * 32 + lo;                                          \
        const int cc_ = ((ks) >> 3) + (j_ & 1) * 2 + hi;                             \
        vc_[j_] = *(const bf16x8v*)((VsB) + r_ * 128 +                               \
                                    ((cc_ ^ swzkey(r_)) << 4));                      \
    }                                                                                \
    f32x16 scA = {}, scB = {};                                                       \
    __builtin_amdgcn_s_setprio(1);                                                   \
    scA = __builtin_amdgcn_mfma_f32_32x32x16_bf16(kc_[0], qf[0], scA, 0, 0, 0);      \
    scB = __builtin_amdgcn_mfma_f32_32x32x16_bf16(kc_[1], qf[1], scB, 0, 0, 0);      \
    scA = __builtin_amdgcn_mfma_f32_32x32x16_bf16(kc_[2], qf[2], scA, 0, 0, 0);      \
    scB = __builtin_amdgcn_mfma_f32_32x32x16_bf16(kc_[3], qf[3], scB, 0, 0, 0);      \
    __builtin_amdgcn_s_setprio(0);                                                   \
    f32x16 sc = scA + scB;                                                           \
    float pe_[16];                                                                   \
    _Pragma("unroll")                                                                \
    for (int r_ = 0; r_ < 16; ++r_)                                                  \
        pe_[r_] = exp2_hw(sc[r_] * EXP_C1);                                          \
    float u0_ = (pe_[0] + pe_[1]) + (pe_[2] + pe_[3]);                               \
    float u1_ = (pe_[4] + pe_[5]) + (pe_[6] + pe_[7]);                               \
    float u2_ = (pe_[8] + pe_[9]) + (pe_[10] + pe_[11]);                             \
    float u3_ = (pe_[12] + pe_[13]) + (pe_[14] + pe_[15]);                           \
    float ss_ = (u0_ + u1_) + (u2_ + u3_);                                           \
    { u32x2 sw_ = pl32swap(ubits(ss_), ubits(ss_));                                  \
      ss_ = fbits(sw_[0]) + fbits(sw_[1]); }                                         \
    lsum += ss_;                                                                     \
    uint32_t a01_ = cvtpk_bf16(pe_[0],  pe_[1]),  a23_ = cvtpk_bf16(pe_[2],  pe_[3]);  \
    uint32_t a45_ = cvtpk_bf16(pe_[4],  pe_[5]),  a67_ = cvtpk_bf16(pe_[6],  pe_[7]);  \
    uint32_t b01_ = cvtpk_bf16(pe_[8],  pe_[9]),  b23_ = cvtpk_bf16(pe_[10], pe_[11]); \
    uint32_t b45_ = cvtpk_bf16(pe_[12], pe_[13]), b67_ = cvtpk_bf16(pe_[14], pe_[15]); \
    u32x2 s0_ = pl32swap(a01_, a45_);                                                \
    u32x2 s1_ = pl32swap(a23_, a67_);                                                \
    u32x2 s2_ = pl32swap(b01_, b45_);                                                \
    u32x2 s3_ = pl32swap(b23_, b67_);                                                \
    u32x4 w0_ = { s0_[0], s1_[0], s0_[1], s1_[1] };                                  \
    u32x4 w1_ = { s2_[0], s3_[0], s2_[1], s3_[1] };                                  \
    bf16x8v pa0_ = __builtin_bit_cast(bf16x8v, w0_);                                 \
    bf16x8v pa1_ = __builtin_bit_cast(bf16x8v, w1_);                                 \
    __builtin_amdgcn_s_setprio(1);                                                   \
    acc0 = __builtin_amdgcn_mfma_f32_32x32x16_bf16(vc_[0], pa0_, acc0, 0, 0, 0);     \
    acc0 = __builtin_amdgcn_mfma_f32_32x32x16_bf16(vc_[1], pa1_, acc0, 0, 0, 0);     \
    acc1 = __builtin_amdgcn_mfma_f32_32x32x16_bf16(vc_[2], pa0_, acc1, 0, 0, 0);     \
    acc1 = __builtin_amdgcn_mfma_f32_32x32x16_bf16(vc_[3], pa1_, acc1, 0, 0, 0);     \
    __builtin_amdgcn_s_setprio(0);                                                   \
} while (0)

__global__ __launch_bounds__(256, 2) void attn_kernel(
    const unsigned short* __restrict__ QKV, const unsigned short* __restrict__ Vt,
    unsigned short* __restrict__ O)
{
    const int tid  = threadIdx.x;
    const int w    = tid >> 6;
    const int lane = tid & 63;
    const int lo = lane & 31;
    const int hi = lane >> 5;

    // T1: XCD-chunked bijective swizzle; 512 blocks = 8 XCDs x 64.
    const int flat = blockIdx.x;
    const int virt = (flat & 7) * 64 + (flat >> 3);
    const int bh = virt >> 4;          // 0..31
    const int qb = virt & 15;          // 0..15
    const int b = bh >> 4, h = bh & 15;
    const int q0 = qb * 128 + w * 32;

    __shared__ __attribute__((aligned(16))) unsigned short Ks[2][KVB * 64];
    __shared__ __attribute__((aligned(16))) unsigned short Vs[2][KVB * 64];

    const unsigned short* Kq  = QKV + (size_t)b * S_LEN * NQKV + DM + h * 64;
    const unsigned short* Vtb = Vt + (size_t)bh * DKH * S_LEN;   // [64][2048]

    const int sr  = tid >> 3, scn = tid & 7;
    const size_t kSrc0 = (size_t)sr * NQKV + ((scn ^ swzkey(sr)) * 8);
    const size_t kSrc1 = (size_t)(sr + 32) * NQKV + ((scn ^ swzkey(sr + 32)) * 8);
    const size_t vSrc0 = (size_t)sr * S_LEN + ((scn ^ swzkey(sr)) * 8);
    const size_t vSrc1 = (size_t)(sr + 32) * S_LEN + ((scn ^ swzkey(sr + 32)) * 8);
    const int dstOff0 = (tid & ~63) * 16;
    const int dstOff1 = dstOff0 + 4096;

#define STAGE_TILE(buf, kvOff)                                                        \
    do {                                                                              \
        __builtin_amdgcn_global_load_lds((gas_void*)(Kq + (kvOff) * NQKV + kSrc0),    \
            (las_void*)((char*)&Ks[buf][0] + dstOff0), 16, 0, 0);                     \
        __builtin_amdgcn_global_load_lds((gas_void*)(Kq + (kvOff) * NQKV + kSrc1),    \
            (las_void*)((char*)&Ks[buf][0] + dstOff1), 16, 0, 0);                     \
        __builtin_amdgcn_global_load_lds((gas_void*)(Vtb + (kvOff) + vSrc0),          \
            (las_void*)((char*)&Vs[buf][0] + dstOff0), 16, 0, 0);                     \
        __builtin_amdgcn_global_load_lds((gas_void*)(Vtb + (kvOff) + vSrc1),          \
            (las_void*)((char*)&Vs[buf][0] + dstOff1), 16, 0, 0);                     \
    } while (0)

    const unsigned short* Qp =
        QKV + ((size_t)b * S_LEN + q0 + lo) * NQKV + h * 64 + hi * 8;
    bf16x8v qf[4];
    #pragma unroll
    for (int s = 0; s < 4; ++s) qf[s] = *(const bf16x8v*)(Qp + s * 16);

    f32x16 acc0 = {}, acc1 = {};
    float lsum = 0.f;

    STAGE_TILE(0, (size_t)0);
    __syncthreads();

    int cur = 0;
    for (int t = 0; t < S_LEN / KVB; ++t) {
        const int nxt = cur ^ 1;
        if (t + 1 < S_LEN / KVB) STAGE_TILE(nxt, (size_t)(t + 1) * KVB);
        const char* KsB = (const char*)&Ks[cur][0];
        const char* VsB = (const char*)&Vs[cur][0];
        LDS_SUB_STEP(KsB, VsB, 0);
        LDS_SUB_STEP(KsB, VsB, 32);
        __syncthreads();
        cur = nxt;
    }
#undef STAGE_TILE

    const float linv = 1.f / lsum;
    unsigned short* Orow = O + ((size_t)b * S_LEN + q0 + lo) * DM + h * 64 + hi * 4;
    #pragma unroll
    for (int g = 0; g < 4; ++g) {
        u16x4 st0, st1;
        #pragma unroll
        for (int k2 = 0; k2 < 4; ++k2) {
            st0[k2] = f2bf(acc0[g * 4 + k2] * linv);
            st1[k2] = f2bf(acc1[g * 4 + k2] * linv);
        }
        *(u16x4*)(Orow + g * 8)      = st0;
        *(u16x4*)(Orow + 32 + g * 8) = st1;
    }
}

// ---------------- host launcher ----------------
extern "C" void kernel_launch(void* const* d_in, const int* in_sizes, int n_in,
                              void* d_out, int out_size, void* d_ws, size_t ws_size,
                              hipStream_t stream)
{
    const float* x    = (const float*)d_in[0];
    const float* Wqkv = (const float*)d_in[1];
    const float* bqkv = (const float*)d_in[2];
    const float* Wout = (const float*)d_in[3];
    const float* bout = (const float*)d_in[4];
    float* out = (float*)d_out;

    char* ws = (char*)d_ws;
    // layout (bytes):
    //  [0,         8388608)  xb (x bf16; dead after QKV GEMM)
    //  [8388608,  14680064)  wqkv_t bf16 [3072][1024]
    //  [14680064, 16777216)  wout_t bf16 [1024][1024]
    //  [16777216, 41943040)  qkvb bf16 [4096][3072]  (LIVE through attn: Q,K read from it)
    //  [41943040, 50331648)  attn_o bf16 [4096][1024]
    //  [50331648, 58720256)  vtb bf16 [32][64][2048]
    unsigned short* xb     = (unsigned short*)(ws);
    unsigned short* wqkv_t = (unsigned short*)(ws + 8388608);
    unsigned short* wout_t = (unsigned short*)(ws + 14680064);
    unsigned short* qkvb   = (unsigned short*)(ws + 16777216);
    unsigned short* attn_o = (unsigned short*)(ws + 41943040);
    unsigned short* vtb    = (unsigned short*)(ws + 50331648);

    prep_kernel<<<6144, 256, 0, stream>>>(x, xb, Wqkv, wqkv_t, Wout, wout_t);
    gemm_bt_kernel<0><<<dim3(NQKV / 128, M_ROWS / 128), 256, 0, stream>>>(
        xb, wqkv_t, bqkv, (void*)qkvb, M_ROWS, NQKV, DM);
    split_v_kernel<<<dim3(S_LEN / 64, BATCH * NH), 256, 0, stream>>>(qkvb, vtb);
    attn_kernel<<<512, 256, 0, stream>>>(qkvb, vtb, attn_o);
    gemm_bt_kernel<1><<<dim3(DM / 128, M_ROWS / 128), 256, 0, stream>>>(
        attn_o, wout_t, bout, (void*)out, M_ROWS, DM, DM);
}